// Round 2
// 1716.437 us; speedup vs baseline: 1.0310x; 1.0310x over previous
//
#include <hip/hip_runtime.h>
#include <math.h>

#define NMAT 50000
#define MPB 8                    // matrices per block: 256 thr = 4 waves = 8 half-waves
#define NBLK (NMAT / MPB)        // 6250

__device__ __forceinline__ float frcp(float x)  { return __builtin_amdgcn_rcpf(x); }
__device__ __forceinline__ float frsq(float x)  { return __builtin_amdgcn_rsqf(x); }
__device__ __forceinline__ float fsqrt_(float x){ return __builtin_amdgcn_sqrtf(x); }

// x + rotate-right-by-n within rows of 16 (VALU pipe, not LDS pipe)
#define DPP_ROR_ADD(x, ctrl) \
  ((x) + __int_as_float(__builtin_amdgcn_update_dpp(0, __float_as_int(x), (ctrl), 0xF, 0xF, false)))

// sum across the 32-lane half-wave, all lanes get the result.
// 4 DPP rotate-adds give every lane its row-of-16 sum; one xor16 swizzle merges.
__device__ __forceinline__ float red32(float x) {
  x = DPP_ROR_ADD(x, 0x121);   // row_ror:1
  x = DPP_ROR_ADD(x, 0x122);   // row_ror:2
  x = DPP_ROR_ADD(x, 0x124);   // row_ror:4
  x = DPP_ROR_ADD(x, 0x128);   // row_ror:8
  x += __shfl_xor(x, 16, 32);
  return x;
}

__device__ __forceinline__ float f4c(const float4& v, int e) {
  return e == 0 ? v.x : e == 1 ? v.y : e == 2 ? v.z : v.w;   // e is compile-time
}

// (256,1): VGPR cap 256. Round-0 evidence: at the (256,2)/128-VGPR cap the
// compiler spilled ~2 GB of scratch writes per launch (WRITE_SIZE 1.94e6 KB vs
// 25 KB logical) and occupancy was scratch-throttled to 7.2 waves/CU anyway.
// Peak live state (~110-125 floats in the Householder loop) fits under 256
// with zero spill; occupancy 8 waves/CU is the same ballpark as before.
__global__ __launch_bounds__(256, 1) void riem_batch(const float* __restrict__ X,
                                                     const float* __restrict__ Y,
                                                     float* __restrict__ partial) {
  const int tid = threadIdx.x;
  const int c   = tid & 31;        // column owned by this lane
  const int hw  = tid >> 5;        // half-wave id within block (0..7)
  const long mat = (long)blockIdx.x * MPB + hw;
  const float* Yp = Y + mat * 1024;
  const float* Xp = X + mat * 1024;

  // Lb[h][j*32+i] = L[i][j] (column j contiguous -> conflict-free writes,
  // uniform-address float4 broadcast reads). No padding needed.
  __shared__ __align__(16) float Lb[MPB][1024];
  __shared__ __align__(16) float vb[MPB][32];
  __shared__ __align__(16) float qb[MPB][32];
  __shared__ float psum[MPB];

  float* Lh = Lb[hw];
  float* vh = vb[hw];
  float* qh = qb[hw];

  // ---- load Y columns: lane c holds Y[:,c] ----
  float m[32];
#pragma unroll
  for (int i = 0; i < 32; ++i) m[i] = Yp[i * 32 + c];

  // ---- square-root-free symmetric elimination Y = L D L^T, L -> LDS ----
  // update: M[i][c] -= L[i][j] * M[j][c]  (L[i][j] uniform from LDS, M[j][c]=m[j] per lane)
  float dc = 1.0f;
#pragma unroll
  for (int j = 0; j < 32; ++j) {
    float piv  = __shfl(m[j], j, 32);          // D[j], uniform per half-wave
    float rinv = frcp(piv);
    if (c == j) dc = piv;
    Lh[j * 32 + c] = m[j] * rinv;              // L[c][j]; diag=1; junk for c<j (never read)
    float mj = m[j];
#pragma unroll
    for (int g = 0; g < 8; ++g) {
      if (4 * g + 3 <= j) continue;            // group has no i > j
      float4 L4 = *(const float4*)(Lh + j * 32 + 4 * g);   // uniform broadcast read
#pragma unroll
      for (int e = 0; e < 4; ++e) {
        int i = 4 * g + e;
        if (i > j) m[i] = fmaf(-f4c(L4, e), mj, m[i]);
      }
    }
  }
  float dsv = frsq(dc);                        // D[c]^{-1/2}
  // m[] dead from here

  // ---- load X, forward solve W = L^{-1} X ----
  float x[32];
#pragma unroll
  for (int i = 0; i < 32; ++i) x[i] = Xp[i * 32 + c];
#pragma unroll
  for (int k = 0; k < 31; ++k) {
    float xk = x[k];
#pragma unroll
    for (int g = 0; g < 8; ++g) {
      if (4 * g + 3 <= k) continue;
      float4 L4 = *(const float4*)(Lh + k * 32 + 4 * g);
#pragma unroll
      for (int e = 0; e < 4; ++e) {
        int i = 4 * g + e;
        if (i > k) x[i] = fmaf(-f4c(L4, e), xk, x[i]);
      }
    }
  }

  // ---- in-register 32x32 butterfly transpose (block-swap recursion) ----
#pragma unroll
  for (int s = 16; s >= 1; s >>= 1) {
    const bool up = (c & s) != 0;
#pragma unroll
    for (int i = 0; i < 32; ++i) {
      if (i & s) continue;                     // compile-time skip
      const int h2 = i | s;
      float send = up ? x[i] : x[h2];
      float rec  = __shfl_xor(send, s, 32);
      x[i]  = up ? rec : x[i];
      x[h2] = up ? x[h2] : rec;
    }
  }

  // ---- second solve V = L^{-1} W^T ----
#pragma unroll
  for (int k = 0; k < 31; ++k) {
    float xk = x[k];
#pragma unroll
    for (int g = 0; g < 8; ++g) {
      if (4 * g + 3 <= k) continue;
      float4 L4 = *(const float4*)(Lh + k * 32 + 4 * g);
#pragma unroll
      for (int e = 0; e < 4; ++e) {
        int i = 4 * g + e;
        if (i > k) x[i] = fmaf(-f4c(L4, e), xk, x[i]);
      }
    }
  }

  // ---- A = D^{-1/2} V D^{-1/2} (dsv broadcast via LDS float4) ----
  vh[c] = dsv;
#pragma unroll
  for (int g = 0; g < 8; ++g) {
    float4 D4 = *(const float4*)(vh + 4 * g);
#pragma unroll
    for (int e = 0; e < 4; ++e) x[4 * g + e] *= f4c(D4, e) * dsv;
  }

  // ---- Householder tridiagonalization; d/e2 extracted in-loop ----
  float d[32], e2[31];
  float e2max = 0.0f, dminv = 1e30f, dmaxv = -1e30f;
#pragma unroll
  for (int k = 0; k < 30; ++k) {
    float colv = x[k];
    float dkk  = __shfl(x[k], k, 32);          // A[k][k], final at step k
    d[k] = dkk; dminv = fminf(dminv, dkk); dmaxv = fmaxf(dmaxv, dkk);
    float sq    = (c > k) ? colv * colv : 0.0f;
    float sigma = red32(sq);                   // ||A[k+1:,k]||^2
    float akk1  = __shfl(x[k], k + 1, 32);
    e2[k] = sigma; e2max = fmaxf(e2max, sigma);
    float nrm   = fsqrt_(sigma);
    float alpha = (akk1 >= 0.0f) ? -nrm : nrm;
    float denom = fmaf(-alpha, akk1, sigma);   // vTv/2
    float tau   = frcp(fmaxf(denom, 1e-35f));  // sigma==0 -> v==0 no-op
    float v     = (c == k + 1) ? (akk1 - alpha) : ((c > k + 1) ? colv : 0.0f);
    vh[c] = v;                                 // broadcast v via LDS
    float acc = 0.0f;
#pragma unroll
    for (int g = 0; g < 8; ++g) {              // acc_c = sum_j A[j][c] v_j
      if (4 * g + 3 <= k) continue;
      float4 V4 = *(const float4*)(vh + 4 * g);
#pragma unroll
      for (int e = 0; e < 4; ++e) {
        int j = 4 * g + e;
        if (j > k) acc = fmaf(x[j], f4c(V4, e), acc);
      }
    }
    float p = tau * acc;
    float K = 0.5f * tau * red32(v * p);
    float q = fmaf(-K, v, p);
    qh[c] = q;                                 // broadcast q via LDS
#pragma unroll
    for (int g = 0; g < 8; ++g) {              // A -= v q^T + q v^T
      if (4 * g + 3 <= k) continue;
      float4 V4 = *(const float4*)(vh + 4 * g);
      float4 Q4 = *(const float4*)(qh + 4 * g);
#pragma unroll
      for (int e = 0; e < 4; ++e) {
        int j = 4 * g + e;
        if (j > k) x[j] = fmaf(-v, f4c(Q4, e), fmaf(-q, f4c(V4, e), x[j]));
      }
    }
  }
  {
    float d30 = __shfl(x[30], 30, 32);
    float d31 = __shfl(x[31], 31, 32);
    float el  = __shfl(x[30], 31, 32);         // trailing subdiagonal
    d[30] = d30; d[31] = d31;
    e2[30] = el * el; e2max = fmaxf(e2max, e2[30]);
    dminv = fminf(dminv, fminf(d30, d31));
    dmaxv = fmaxf(dmaxv, fmaxf(d30, d31));
  }
  // x[] dead from here

  // ---- Gershgorin bounds ----
  float er = 2.0f * fsqrt_(e2max);
  float lo = fmaxf(dminv - er, 1e-3f);
  float hi = dmaxv + er;

  // ---- bisection with Sturm counts: lane c -> eigenvalue #c (pure VALU) ----
  for (int it = 0; it < 18; ++it) {
    float mid = 0.5f * (lo + hi);
    float qq  = d[0] - mid;
    qq = (fabsf(qq) < 1e-30f) ? -1e-30f : qq;
    int cnt = (qq < 0.0f) ? 1 : 0;
#pragma unroll
    for (int i = 1; i < 32; ++i) {
      qq = (d[i] - mid) - e2[i - 1] * frcp(qq);
      qq = (fabsf(qq) < 1e-30f) ? -1e-30f : qq;
      cnt += (qq < 0.0f) ? 1 : 0;
    }
    bool le = (cnt <= c);
    lo = le ? mid : lo;
    hi = le ? hi : mid;
  }

  float lam = 0.5f * (lo + hi);
  float lg  = __logf(lam);
  float s   = red32(lg * lg);
  float db  = fsqrt_(s);                       // d(x_b, y_b)

  if (c == 0) psum[hw] = db;
  __syncthreads();
  if (tid == 0) {
    float t = 0.0f;
#pragma unroll
    for (int i = 0; i < MPB; ++i) t += psum[i];
    partial[blockIdx.x] = t;
  }
}

__global__ __launch_bounds__(256) void riem_finish(const float* __restrict__ partial,
                                                   float* __restrict__ out) {
  float acc = 0.0f;
  for (int i = threadIdx.x; i < NBLK; i += 256) acc += partial[i];
  acc += __shfl_xor(acc, 1);
  acc += __shfl_xor(acc, 2);
  acc += __shfl_xor(acc, 4);
  acc += __shfl_xor(acc, 8);
  acc += __shfl_xor(acc, 16);
  acc += __shfl_xor(acc, 32);
  __shared__ float ps[4];
  if ((threadIdx.x & 63) == 0) ps[threadIdx.x >> 6] = acc;
  __syncthreads();
  if (threadIdx.x == 0)
    out[0] = (ps[0] + ps[1] + ps[2] + ps[3]) * (1.0f / (float)NMAT);
}

extern "C" void kernel_launch(void* const* d_in, const int* in_sizes, int n_in,
                              void* d_out, int out_size, void* d_ws, size_t ws_size,
                              hipStream_t stream) {
  const float* x = (const float*)d_in[0];
  const float* y = (const float*)d_in[1];
  float* out  = (float*)d_out;
  float* part = (float*)d_ws;   // NBLK floats = 25 KB
  riem_batch<<<NBLK, 256, 0, stream>>>(x, y, part);
  riem_finish<<<1, 256, 0, stream>>>(part, out);
}

// Round 3
// 1609.600 us; speedup vs baseline: 1.0994x; 1.0664x over previous
//
#include <hip/hip_runtime.h>
#include <math.h>

#define NMAT 50000
#define MPB 8                    // matrices per block: 256 thr = 4 waves = 8 half-waves
#define NBLK (NMAT / MPB)        // 6250

__device__ __forceinline__ float frcp(float x)  { return __builtin_amdgcn_rcpf(x); }
__device__ __forceinline__ float frsq(float x)  { return __builtin_amdgcn_rsqf(x); }
__device__ __forceinline__ float fsqrt_(float x){ return __builtin_amdgcn_sqrtf(x); }

// x + rotate-right-by-n within rows of 16 (VALU pipe, not LDS pipe)
#define DPP_ROR_ADD(x, ctrl) \
  ((x) + __int_as_float(__builtin_amdgcn_update_dpp(0, __float_as_int(x), (ctrl), 0xF, 0xF, false)))

// sum across the 32-lane half-wave, all lanes get the result.
// 4 DPP rotate-adds give every lane its row-of-16 sum; one xor16 swizzle merges.
__device__ __forceinline__ float red32(float x) {
  x = DPP_ROR_ADD(x, 0x121);   // row_ror:1
  x = DPP_ROR_ADD(x, 0x122);   // row_ror:2
  x = DPP_ROR_ADD(x, 0x124);   // row_ror:4
  x = DPP_ROR_ADD(x, 0x128);   // row_ror:8
  x += __shfl_xor(x, 16, 32);
  return x;
}

__device__ __forceinline__ float f4c(const float4& v, int e) {
  return e == 0 ? v.x : e == 1 ? v.y : e == 2 ? v.z : v.w;   // e is compile-time
}

// (256,2): 128-VGPR cap. Round-2 evidence: at 256 VGPR only ~1 wave/SIMD is
// resident and the kernel is VALU-latency-bound (VALUBusy 40%, time unchanged
// vs the spilling 128-VGPR version). The d/e2 arrays (63 wave-uniform floats)
// are what blow the 128 budget during Householder -> stream them to a separate
// LDS stash while x[32] is live, reload after x[] dies. Peak live ~75 floats
// in every phase -> fits 128 clean -> 4 waves/SIMD, LDS 37.3KB*4 = 149KB/CU.
__global__ __launch_bounds__(256, 2) void riem_batch(const float* __restrict__ X,
                                                     const float* __restrict__ Y,
                                                     float* __restrict__ partial) {
  const int tid = threadIdx.x;
  const int c   = tid & 31;        // column owned by this lane
  const int hw  = tid >> 5;        // half-wave id within block (0..7)
  const long mat = (long)blockIdx.x * MPB + hw;
  const float* Yp = Y + mat * 1024;
  const float* Xp = X + mat * 1024;

  // Lb[h][j*32+i] = L[i][j] (column j contiguous -> conflict-free writes,
  // uniform-address float4 broadcast reads). No padding needed.
  __shared__ __align__(16) float Lb[MPB][1024];
  __shared__ __align__(16) float vb[MPB][32];
  __shared__ __align__(16) float qb[MPB][32];
  __shared__ __align__(16) float sb[MPB][64];   // d/e2 stash: [0..31]=d, [32..62]=e2
  __shared__ float psum[MPB];

  float* Lh = Lb[hw];
  float* vh = vb[hw];
  float* qh = qb[hw];
  float* sh = sb[hw];

  // ---- load Y columns: lane c holds Y[:,c] ----
  float m[32];
#pragma unroll
  for (int i = 0; i < 32; ++i) m[i] = Yp[i * 32 + c];

  // ---- square-root-free symmetric elimination Y = L D L^T, L -> LDS ----
  // update: M[i][c] -= L[i][j] * M[j][c]  (L[i][j] uniform from LDS, M[j][c]=m[j] per lane)
  float dc = 1.0f;
#pragma unroll
  for (int j = 0; j < 32; ++j) {
    float piv  = __shfl(m[j], j, 32);          // D[j], uniform per half-wave
    float rinv = frcp(piv);
    if (c == j) dc = piv;
    Lh[j * 32 + c] = m[j] * rinv;              // L[c][j]; diag=1; junk for c<j (never read)
    float mj = m[j];
#pragma unroll
    for (int g = 0; g < 8; ++g) {
      if (4 * g + 3 <= j) continue;            // group has no i > j
      float4 L4 = *(const float4*)(Lh + j * 32 + 4 * g);   // uniform broadcast read
#pragma unroll
      for (int e = 0; e < 4; ++e) {
        int i = 4 * g + e;
        if (i > j) m[i] = fmaf(-f4c(L4, e), mj, m[i]);
      }
    }
  }
  float dsv = frsq(dc);                        // D[c]^{-1/2}
  // m[] dead from here

  // ---- load X, forward solve W = L^{-1} X ----
  float x[32];
#pragma unroll
  for (int i = 0; i < 32; ++i) x[i] = Xp[i * 32 + c];
#pragma unroll
  for (int k = 0; k < 31; ++k) {
    float xk = x[k];
#pragma unroll
    for (int g = 0; g < 8; ++g) {
      if (4 * g + 3 <= k) continue;
      float4 L4 = *(const float4*)(Lh + k * 32 + 4 * g);
#pragma unroll
      for (int e = 0; e < 4; ++e) {
        int i = 4 * g + e;
        if (i > k) x[i] = fmaf(-f4c(L4, e), xk, x[i]);
      }
    }
  }

  // ---- in-register 32x32 butterfly transpose (block-swap recursion) ----
#pragma unroll
  for (int s = 16; s >= 1; s >>= 1) {
    const bool up = (c & s) != 0;
#pragma unroll
    for (int i = 0; i < 32; ++i) {
      if (i & s) continue;                     // compile-time skip
      const int h2 = i | s;
      float send = up ? x[i] : x[h2];
      float rec  = __shfl_xor(send, s, 32);
      x[i]  = up ? rec : x[i];
      x[h2] = up ? x[h2] : rec;
    }
  }

  // ---- second solve V = L^{-1} W^T ----
#pragma unroll
  for (int k = 0; k < 31; ++k) {
    float xk = x[k];
#pragma unroll
    for (int g = 0; g < 8; ++g) {
      if (4 * g + 3 <= k) continue;
      float4 L4 = *(const float4*)(Lh + k * 32 + 4 * g);
#pragma unroll
      for (int e = 0; e < 4; ++e) {
        int i = 4 * g + e;
        if (i > k) x[i] = fmaf(-f4c(L4, e), xk, x[i]);
      }
    }
  }

  // ---- A = D^{-1/2} V D^{-1/2} (dsv broadcast via LDS float4) ----
  vh[c] = dsv;
#pragma unroll
  for (int g = 0; g < 8; ++g) {
    float4 D4 = *(const float4*)(vh + 4 * g);
#pragma unroll
    for (int e = 0; e < 4; ++e) x[4 * g + e] *= f4c(D4, e) * dsv;
  }

  // ---- Householder tridiagonalization; d/e2 streamed to the LDS stash.
  //      dkk/sigma are uniform across the half-wave: all lanes store the same
  //      value to the same address (no predication, single winner). Keeping
  //      them in VGPRs alongside x[32] is what forced 256-reg allocation. ----
  float e2max = 0.0f, dminv = 1e30f, dmaxv = -1e30f;
#pragma unroll
  for (int k = 0; k < 30; ++k) {
    float colv = x[k];
    float dkk  = __shfl(x[k], k, 32);          // A[k][k], final at step k
    dminv = fminf(dminv, dkk); dmaxv = fmaxf(dmaxv, dkk);
    float sq    = (c > k) ? colv * colv : 0.0f;
    float sigma = red32(sq);                   // ||A[k+1:,k]||^2
    float akk1  = __shfl(x[k], k + 1, 32);
    e2max = fmaxf(e2max, sigma);
    sh[k] = dkk;                               // stash d[k]
    sh[32 + k] = sigma;                        // stash e2[k]
    float nrm   = fsqrt_(sigma);
    float alpha = (akk1 >= 0.0f) ? -nrm : nrm;
    float denom = fmaf(-alpha, akk1, sigma);   // vTv/2
    float tau   = frcp(fmaxf(denom, 1e-35f));  // sigma==0 -> v==0 no-op
    float v     = (c == k + 1) ? (akk1 - alpha) : ((c > k + 1) ? colv : 0.0f);
    vh[c] = v;                                 // broadcast v via LDS
    float acc = 0.0f;
#pragma unroll
    for (int g = 0; g < 8; ++g) {              // acc_c = sum_j A[j][c] v_j
      if (4 * g + 3 <= k) continue;
      float4 V4 = *(const float4*)(vh + 4 * g);
#pragma unroll
      for (int e = 0; e < 4; ++e) {
        int j = 4 * g + e;
        if (j > k) acc = fmaf(x[j], f4c(V4, e), acc);
      }
    }
    float p = tau * acc;
    float K = 0.5f * tau * red32(v * p);
    float q = fmaf(-K, v, p);
    qh[c] = q;                                 // broadcast q via LDS
#pragma unroll
    for (int g = 0; g < 8; ++g) {              // A -= v q^T + q v^T
      if (4 * g + 3 <= k) continue;
      float4 V4 = *(const float4*)(vh + 4 * g);
      float4 Q4 = *(const float4*)(qh + 4 * g);
#pragma unroll
      for (int e = 0; e < 4; ++e) {
        int j = 4 * g + e;
        if (j > k) x[j] = fmaf(-v, f4c(Q4, e), fmaf(-q, f4c(V4, e), x[j]));
      }
    }
  }
  {
    float d30 = __shfl(x[30], 30, 32);
    float d31 = __shfl(x[31], 31, 32);
    float el  = __shfl(x[30], 31, 32);         // trailing subdiagonal
    float e30 = el * el;
    sh[30] = d30; sh[31] = d31; sh[62] = e30;
    e2max = fmaxf(e2max, e30);
    dminv = fminf(dminv, fminf(d30, d31));
    dmaxv = fmaxf(dmaxv, fmaxf(d30, d31));
  }
  // x[] dead from here -> its registers take d/e2 back; no live-range overlap

  // ---- reload wave-uniform d/e2 from the stash (float4 broadcast reads) ----
  float d[32], e2[31];
#pragma unroll
  for (int g = 0; g < 8; ++g) {
    float4 D4 = *(const float4*)(sh + 4 * g);
    d[4 * g + 0] = D4.x; d[4 * g + 1] = D4.y;
    d[4 * g + 2] = D4.z; d[4 * g + 3] = D4.w;
  }
#pragma unroll
  for (int g = 0; g < 8; ++g) {
    float4 E4 = *(const float4*)(sh + 32 + 4 * g);
    e2[4 * g + 0] = E4.x;
    if (4 * g + 1 < 31) e2[4 * g + 1] = E4.y;
    if (4 * g + 2 < 31) e2[4 * g + 2] = E4.z;
    if (4 * g + 3 < 31) e2[4 * g + 3] = E4.w;   // g=7: sh[63] unused, skipped
  }

  // ---- Gershgorin bounds ----
  float er = 2.0f * fsqrt_(e2max);
  float lo = fmaxf(dminv - er, 1e-3f);
  float hi = dmaxv + er;

  // ---- bisection with Sturm counts: lane c -> eigenvalue #c (pure VALU) ----
  for (int it = 0; it < 18; ++it) {
    float mid = 0.5f * (lo + hi);
    float qq  = d[0] - mid;
    qq = (fabsf(qq) < 1e-30f) ? -1e-30f : qq;
    int cnt = (qq < 0.0f) ? 1 : 0;
#pragma unroll
    for (int i = 1; i < 32; ++i) {
      qq = (d[i] - mid) - e2[i - 1] * frcp(qq);
      qq = (fabsf(qq) < 1e-30f) ? -1e-30f : qq;
      cnt += (qq < 0.0f) ? 1 : 0;
    }
    bool le = (cnt <= c);
    lo = le ? mid : lo;
    hi = le ? hi : mid;
  }

  float lam = 0.5f * (lo + hi);
  float lg  = __logf(lam);
  float s   = red32(lg * lg);
  float db  = fsqrt_(s);                       // d(x_b, y_b)

  if (c == 0) psum[hw] = db;
  __syncthreads();
  if (tid == 0) {
    float t = 0.0f;
#pragma unroll
    for (int i = 0; i < MPB; ++i) t += psum[i];
    partial[blockIdx.x] = t;
  }
}

__global__ __launch_bounds__(256) void riem_finish(const float* __restrict__ partial,
                                                   float* __restrict__ out) {
  float acc = 0.0f;
  for (int i = threadIdx.x; i < NBLK; i += 256) acc += partial[i];
  acc += __shfl_xor(acc, 1);
  acc += __shfl_xor(acc, 2);
  acc += __shfl_xor(acc, 4);
  acc += __shfl_xor(acc, 8);
  acc += __shfl_xor(acc, 16);
  acc += __shfl_xor(acc, 32);
  __shared__ float ps[4];
  if ((threadIdx.x & 63) == 0) ps[threadIdx.x >> 6] = acc;
  __syncthreads();
  if (threadIdx.x == 0)
    out[0] = (ps[0] + ps[1] + ps[2] + ps[3]) * (1.0f / (float)NMAT);
}

extern "C" void kernel_launch(void* const* d_in, const int* in_sizes, int n_in,
                              void* d_out, int out_size, void* d_ws, size_t ws_size,
                              hipStream_t stream) {
  const float* x = (const float*)d_in[0];
  const float* y = (const float*)d_in[1];
  float* out  = (float*)d_out;
  float* part = (float*)d_ws;   // NBLK floats = 25 KB
  riem_batch<<<NBLK, 256, 0, stream>>>(x, y, part);
  riem_finish<<<1, 256, 0, stream>>>(part, out);
}

// Round 4
// 864.909 us; speedup vs baseline: 2.0461x; 1.8610x over previous
//
#include <hip/hip_runtime.h>
#include <math.h>

#define NMAT 50000
#define MPB 8                    // matrices per block: 256 thr = 4 waves = 8 half-waves
#define NBLK (NMAT / MPB)        // 6250

__device__ __forceinline__ float frcp(float x)  { return __builtin_amdgcn_rcpf(x); }
__device__ __forceinline__ float frsq(float x)  { return __builtin_amdgcn_rsqf(x); }
__device__ __forceinline__ float fsqrt_(float x){ return __builtin_amdgcn_sqrtf(x); }

// Scheduler fence: nothing moves across. Used at unrolled-iteration boundaries
// to stop the machine scheduler from hoisting LDS reads across iterations --
// that hoisting is what inflated pressure past the VGPR cap and caused ~1.9 GB
// of scratch traffic per launch (rounds 0-3 evidence: spills ~constant even
// with 256-VGPR headroom; occupancy scratch-throttled to 22%).
#define SCHED_FENCE() __builtin_amdgcn_sched_barrier(0)

// x + rotate-right-by-n within rows of 16 (VALU pipe, not LDS pipe)
#define DPP_ROR_ADD(x, ctrl) \
  ((x) + __int_as_float(__builtin_amdgcn_update_dpp(0, __float_as_int(x), (ctrl), 0xF, 0xF, false)))

// sum across the 32-lane half-wave, all lanes get the result.
__device__ __forceinline__ float red32(float x) {
  x = DPP_ROR_ADD(x, 0x121);   // row_ror:1
  x = DPP_ROR_ADD(x, 0x122);   // row_ror:2
  x = DPP_ROR_ADD(x, 0x124);   // row_ror:4
  x = DPP_ROR_ADD(x, 0x128);   // row_ror:8
  x += __shfl_xor(x, 16, 32);
  return x;
}

__device__ __forceinline__ float f4c(const float4& v, int e) {
  return e == 0 ? v.x : e == 1 ? v.y : e == 2 ? v.z : v.w;   // e is compile-time
}

// (256,2): 128-VGPR cap -> up to 4 waves/SIMD; LDS 37.3KB -> 4 blocks/CU.
__global__ __launch_bounds__(256, 2) void riem_batch(const float* __restrict__ X,
                                                     const float* __restrict__ Y,
                                                     float* __restrict__ partial) {
  const int tid = threadIdx.x;
  const int c   = tid & 31;        // column owned by this lane
  const int hw  = tid >> 5;        // half-wave id within block (0..7)
  const long mat = (long)blockIdx.x * MPB + hw;
  const float* Yp = Y + mat * 1024;
  const float* Xp = X + mat * 1024;

  // Lb[h][j*32+i] = L[i][j] (column j contiguous -> conflict-free writes,
  // uniform-address float4 broadcast reads). No padding needed.
  __shared__ __align__(16) float Lb[MPB][1024];
  __shared__ __align__(16) float vb[MPB][32];
  __shared__ __align__(16) float qb[MPB][32];
  __shared__ __align__(16) float sb[MPB][64];   // d/e2 stash: [0..31]=d, [32..62]=e2
  __shared__ float psum[MPB];

  float* Lh = Lb[hw];
  float* vh = vb[hw];
  float* qh = qb[hw];
  float* sh = sb[hw];

  // ---- load Y columns: lane c holds Y[:,c] ----
  float m[32];
#pragma unroll
  for (int i = 0; i < 32; ++i) m[i] = Yp[i * 32 + c];

  // ---- square-root-free symmetric elimination Y = L D L^T, L -> LDS ----
  float dc = 1.0f;
#pragma unroll
  for (int j = 0; j < 32; ++j) {
    float piv  = __shfl(m[j], j, 32);          // D[j], uniform per half-wave
    float rinv = frcp(piv);
    if (c == j) dc = piv;
    Lh[j * 32 + c] = m[j] * rinv;              // L[c][j]; diag=1; junk for c<j (never read)
    float mj = m[j];
#pragma unroll
    for (int g = 0; g < 8; ++g) {
      if (4 * g + 3 <= j) continue;            // group has no i > j
      float4 L4 = *(const float4*)(Lh + j * 32 + 4 * g);   // uniform broadcast read
#pragma unroll
      for (int e = 0; e < 4; ++e) {
        int i = 4 * g + e;
        if (i > j) m[i] = fmaf(-f4c(L4, e), mj, m[i]);
      }
    }
    SCHED_FENCE();                             // no cross-iteration hoisting
  }
  float dsv = frsq(dc);                        // D[c]^{-1/2}
  // m[] dead from here

  // ---- load X, forward solve W = L^{-1} X ----
  float x[32];
#pragma unroll
  for (int i = 0; i < 32; ++i) x[i] = Xp[i * 32 + c];
#pragma unroll
  for (int k = 0; k < 31; ++k) {
    float xk = x[k];
#pragma unroll
    for (int g = 0; g < 8; ++g) {
      if (4 * g + 3 <= k) continue;
      float4 L4 = *(const float4*)(Lh + k * 32 + 4 * g);
#pragma unroll
      for (int e = 0; e < 4; ++e) {
        int i = 4 * g + e;
        if (i > k) x[i] = fmaf(-f4c(L4, e), xk, x[i]);
      }
    }
    SCHED_FENCE();
  }

  // ---- in-register 32x32 butterfly transpose (block-swap recursion) ----
#pragma unroll
  for (int s = 16; s >= 1; s >>= 1) {
    const bool up = (c & s) != 0;
#pragma unroll
    for (int i = 0; i < 32; ++i) {
      if (i & s) continue;                     // compile-time skip
      const int h2 = i | s;
      float send = up ? x[i] : x[h2];
      float rec  = __shfl_xor(send, s, 32);
      x[i]  = up ? rec : x[i];
      x[h2] = up ? x[h2] : rec;
    }
  }

  // ---- second solve V = L^{-1} W^T ----
#pragma unroll
  for (int k = 0; k < 31; ++k) {
    float xk = x[k];
#pragma unroll
    for (int g = 0; g < 8; ++g) {
      if (4 * g + 3 <= k) continue;
      float4 L4 = *(const float4*)(Lh + k * 32 + 4 * g);
#pragma unroll
      for (int e = 0; e < 4; ++e) {
        int i = 4 * g + e;
        if (i > k) x[i] = fmaf(-f4c(L4, e), xk, x[i]);
      }
    }
    SCHED_FENCE();
  }

  // ---- A = D^{-1/2} V D^{-1/2} (dsv broadcast via LDS float4) ----
  vh[c] = dsv;
#pragma unroll
  for (int g = 0; g < 8; ++g) {
    float4 D4 = *(const float4*)(vh + 4 * g);
#pragma unroll
    for (int e = 0; e < 4; ++e) x[4 * g + e] *= f4c(D4, e) * dsv;
  }

  // ---- Householder tridiagonalization; d/e2 streamed to the LDS stash
  //      (wave-uniform values; keeping them in VGPRs alongside x[32] was
  //      architectural overpressure) ----
  float e2max = 0.0f, dminv = 1e30f, dmaxv = -1e30f;
#pragma unroll
  for (int k = 0; k < 30; ++k) {
    float colv = x[k];
    float dkk  = __shfl(x[k], k, 32);          // A[k][k], final at step k
    dminv = fminf(dminv, dkk); dmaxv = fmaxf(dmaxv, dkk);
    float sq    = (c > k) ? colv * colv : 0.0f;
    float sigma = red32(sq);                   // ||A[k+1:,k]||^2
    float akk1  = __shfl(x[k], k + 1, 32);
    e2max = fmaxf(e2max, sigma);
    sh[k] = dkk;                               // stash d[k]
    sh[32 + k] = sigma;                        // stash e2[k]
    float nrm   = fsqrt_(sigma);
    float alpha = (akk1 >= 0.0f) ? -nrm : nrm;
    float denom = fmaf(-alpha, akk1, sigma);   // vTv/2
    float tau   = frcp(fmaxf(denom, 1e-35f));  // sigma==0 -> v==0 no-op
    float v     = (c == k + 1) ? (akk1 - alpha) : ((c > k + 1) ? colv : 0.0f);
    vh[c] = v;                                 // broadcast v via LDS
    float acc = 0.0f;
#pragma unroll
    for (int g = 0; g < 8; ++g) {              // acc_c = sum_j A[j][c] v_j
      if (4 * g + 3 <= k) continue;
      float4 V4 = *(const float4*)(vh + 4 * g);
#pragma unroll
      for (int e = 0; e < 4; ++e) {
        int j = 4 * g + e;
        if (j > k) acc = fmaf(x[j], f4c(V4, e), acc);
      }
    }
    float p = tau * acc;
    float K = 0.5f * tau * red32(v * p);
    float q = fmaf(-K, v, p);
    qh[c] = q;                                 // broadcast q via LDS
#pragma unroll
    for (int g = 0; g < 8; ++g) {              // A -= v q^T + q v^T
      if (4 * g + 3 <= k) continue;
      float4 V4 = *(const float4*)(vh + 4 * g);
      float4 Q4 = *(const float4*)(qh + 4 * g);
#pragma unroll
      for (int e = 0; e < 4; ++e) {
        int j = 4 * g + e;
        if (j > k) x[j] = fmaf(-v, f4c(Q4, e), fmaf(-q, f4c(V4, e), x[j]));
      }
    }
    SCHED_FENCE();                             // biggest spill site: pin hard
  }
  {
    float d30 = __shfl(x[30], 30, 32);
    float d31 = __shfl(x[31], 31, 32);
    float el  = __shfl(x[30], 31, 32);         // trailing subdiagonal
    float e30 = el * el;
    sh[30] = d30; sh[31] = d31; sh[62] = e30;
    e2max = fmaxf(e2max, e30);
    dminv = fminf(dminv, fminf(d30, d31));
    dmaxv = fmaxf(dmaxv, fmaxf(d30, d31));
  }
  // x[] dead from here -> its registers take d/e2 back; no live-range overlap

  // ---- reload wave-uniform d/e2 from the stash (float4 broadcast reads) ----
  float d[32], e2[31];
#pragma unroll
  for (int g = 0; g < 8; ++g) {
    float4 D4 = *(const float4*)(sh + 4 * g);
    d[4 * g + 0] = D4.x; d[4 * g + 1] = D4.y;
    d[4 * g + 2] = D4.z; d[4 * g + 3] = D4.w;
  }
#pragma unroll
  for (int g = 0; g < 8; ++g) {
    float4 E4 = *(const float4*)(sh + 32 + 4 * g);
    e2[4 * g + 0] = E4.x;
    if (4 * g + 1 < 31) e2[4 * g + 1] = E4.y;
    if (4 * g + 2 < 31) e2[4 * g + 2] = E4.z;
    if (4 * g + 3 < 31) e2[4 * g + 3] = E4.w;   // g=7: sh[63] unused, skipped
  }

  // ---- Gershgorin bounds ----
  float er = 2.0f * fsqrt_(e2max);
  float lo = fmaxf(dminv - er, 1e-3f);
  float hi = dmaxv + er;

  // ---- bisection with Sturm counts: lane c -> eigenvalue #c (pure VALU) ----
  for (int it = 0; it < 18; ++it) {
    float mid = 0.5f * (lo + hi);
    float qq  = d[0] - mid;
    qq = (fabsf(qq) < 1e-30f) ? -1e-30f : qq;
    int cnt = (qq < 0.0f) ? 1 : 0;
#pragma unroll
    for (int i = 1; i < 32; ++i) {
      qq = (d[i] - mid) - e2[i - 1] * frcp(qq);
      qq = (fabsf(qq) < 1e-30f) ? -1e-30f : qq;
      cnt += (qq < 0.0f) ? 1 : 0;
    }
    bool le = (cnt <= c);
    lo = le ? mid : lo;
    hi = le ? hi : mid;
  }

  float lam = 0.5f * (lo + hi);
  float lg  = __logf(lam);
  float s   = red32(lg * lg);
  float db  = fsqrt_(s);                       // d(x_b, y_b)

  if (c == 0) psum[hw] = db;
  __syncthreads();
  if (tid == 0) {
    float t = 0.0f;
#pragma unroll
    for (int i = 0; i < MPB; ++i) t += psum[i];
    partial[blockIdx.x] = t;
  }
}

__global__ __launch_bounds__(256) void riem_finish(const float* __restrict__ partial,
                                                   float* __restrict__ out) {
  float acc = 0.0f;
  for (int i = threadIdx.x; i < NBLK; i += 256) acc += partial[i];
  acc += __shfl_xor(acc, 1);
  acc += __shfl_xor(acc, 2);
  acc += __shfl_xor(acc, 4);
  acc += __shfl_xor(acc, 8);
  acc += __shfl_xor(acc, 16);
  acc += __shfl_xor(acc, 32);
  __shared__ float ps[4];
  if ((threadIdx.x & 63) == 0) ps[threadIdx.x >> 6] = acc;
  __syncthreads();
  if (threadIdx.x == 0)
    out[0] = (ps[0] + ps[1] + ps[2] + ps[3]) * (1.0f / (float)NMAT);
}

extern "C" void kernel_launch(void* const* d_in, const int* in_sizes, int n_in,
                              void* d_out, int out_size, void* d_ws, size_t ws_size,
                              hipStream_t stream) {
  const float* x = (const float*)d_in[0];
  const float* y = (const float*)d_in[1];
  float* out  = (float*)d_out;
  float* part = (float*)d_ws;   // NBLK floats = 25 KB
  riem_batch<<<NBLK, 256, 0, stream>>>(x, y, part);
  riem_finish<<<1, 256, 0, stream>>>(part, out);
}

// Round 5
// 804.825 us; speedup vs baseline: 2.1988x; 1.0747x over previous
//
#include <hip/hip_runtime.h>
#include <math.h>

#define NMAT 50000
#define MPB 8                    // matrices per block: 256 thr = 4 waves = 8 half-waves
#define NBLK (NMAT / MPB)        // 6250

__device__ __forceinline__ float frcp(float x)  { return __builtin_amdgcn_rcpf(x); }
__device__ __forceinline__ float frsq(float x)  { return __builtin_amdgcn_rsqf(x); }
__device__ __forceinline__ float fsqrt_(float x){ return __builtin_amdgcn_sqrtf(x); }

// Scheduler fence at unrolled-iteration boundaries: stops the machine
// scheduler from hoisting LDS reads across iterations. Round-4 evidence: this
// alone removed ~1.9 GB of scratch traffic (WRITE 1.91e6 -> 195 KB), VGPR
// 128 -> 76, dur 1385 -> 645 us. Do not remove.
#define SCHED_FENCE() __builtin_amdgcn_sched_barrier(0)

// x + rotate-right-by-n within rows of 16 (VALU pipe, not LDS pipe)
#define DPP_ROR_ADD(x, ctrl) \
  ((x) + __int_as_float(__builtin_amdgcn_update_dpp(0, __float_as_int(x), (ctrl), 0xF, 0xF, false)))

// sum across the 32-lane half-wave, all lanes get the result.
__device__ __forceinline__ float red32(float x) {
  x = DPP_ROR_ADD(x, 0x121);   // row_ror:1
  x = DPP_ROR_ADD(x, 0x122);   // row_ror:2
  x = DPP_ROR_ADD(x, 0x124);   // row_ror:4
  x = DPP_ROR_ADD(x, 0x128);   // row_ror:8
  x += __shfl_xor(x, 16, 32);
  return x;
}

__device__ __forceinline__ float f4c(const float4& v, int e) {
  return e == 0 ? v.x : e == 1 ? v.y : e == 2 ? v.z : v.w;   // e is compile-time
}

// (256,2): 128-VGPR cap -> up to 4 waves/SIMD; LDS 37.3KB -> 4 blocks/CU.
__global__ __launch_bounds__(256, 2) void riem_batch(const float* __restrict__ X,
                                                     const float* __restrict__ Y,
                                                     float* __restrict__ partial) {
  const int tid = threadIdx.x;
  const int c   = tid & 31;        // column owned by this lane
  const int hw  = tid >> 5;        // half-wave id within block (0..7)
  const long mat = (long)blockIdx.x * MPB + hw;
  const float* Yp = Y + mat * 1024;
  const float* Xp = X + mat * 1024;

  // Lb[h][j*32+i] = L[i][j] (column j contiguous -> conflict-free writes,
  // uniform-address float4 broadcast reads). No padding needed.
  __shared__ __align__(16) float Lb[MPB][1024];
  __shared__ __align__(16) float vb[MPB][32];
  __shared__ __align__(16) float qb[MPB][32];
  __shared__ __align__(16) float sb[MPB][64];   // d/e2 stash: [0..31]=d, [32..62]=e2
  __shared__ float psum[MPB];

  float* Lh = Lb[hw];
  float* vh = vb[hw];
  float* qh = qb[hw];
  float* sh = sb[hw];

  // ---- load Y columns: lane c holds Y[:,c] ----
  float m[32];
#pragma unroll
  for (int i = 0; i < 32; ++i) m[i] = Yp[i * 32 + c];

  // ---- square-root-free symmetric elimination Y = L D L^T, L -> LDS ----
  float dc = 1.0f;
#pragma unroll
  for (int j = 0; j < 32; ++j) {
    float piv  = __shfl(m[j], j, 32);          // D[j], uniform per half-wave
    float rinv = frcp(piv);
    if (c == j) dc = piv;
    Lh[j * 32 + c] = m[j] * rinv;              // L[c][j]; diag=1; junk for c<j (never read)
    float mj = m[j];
#pragma unroll
    for (int g = 0; g < 8; ++g) {
      if (4 * g + 3 <= j) continue;            // group has no i > j
      float4 L4 = *(const float4*)(Lh + j * 32 + 4 * g);   // uniform broadcast read
#pragma unroll
      for (int e = 0; e < 4; ++e) {
        int i = 4 * g + e;
        if (i > j) m[i] = fmaf(-f4c(L4, e), mj, m[i]);
      }
    }
    SCHED_FENCE();                             // no cross-iteration hoisting
  }
  float dsv = frsq(dc);                        // D[c]^{-1/2}
  // m[] dead from here

  // ---- load X, forward solve W = L^{-1} X ----
  float x[32];
#pragma unroll
  for (int i = 0; i < 32; ++i) x[i] = Xp[i * 32 + c];
#pragma unroll
  for (int k = 0; k < 31; ++k) {
    float xk = x[k];
#pragma unroll
    for (int g = 0; g < 8; ++g) {
      if (4 * g + 3 <= k) continue;
      float4 L4 = *(const float4*)(Lh + k * 32 + 4 * g);
#pragma unroll
      for (int e = 0; e < 4; ++e) {
        int i = 4 * g + e;
        if (i > k) x[i] = fmaf(-f4c(L4, e), xk, x[i]);
      }
    }
    SCHED_FENCE();
  }

  // ---- in-register 32x32 butterfly transpose (block-swap recursion) ----
#pragma unroll
  for (int s = 16; s >= 1; s >>= 1) {
    const bool up = (c & s) != 0;
#pragma unroll
    for (int i = 0; i < 32; ++i) {
      if (i & s) continue;                     // compile-time skip
      const int h2 = i | s;
      float send = up ? x[i] : x[h2];
      float rec  = __shfl_xor(send, s, 32);
      x[i]  = up ? rec : x[i];
      x[h2] = up ? x[h2] : rec;
    }
  }

  // ---- second solve V = L^{-1} W^T ----
#pragma unroll
  for (int k = 0; k < 31; ++k) {
    float xk = x[k];
#pragma unroll
    for (int g = 0; g < 8; ++g) {
      if (4 * g + 3 <= k) continue;
      float4 L4 = *(const float4*)(Lh + k * 32 + 4 * g);
#pragma unroll
      for (int e = 0; e < 4; ++e) {
        int i = 4 * g + e;
        if (i > k) x[i] = fmaf(-f4c(L4, e), xk, x[i]);
      }
    }
    SCHED_FENCE();
  }

  // ---- A = D^{-1/2} V D^{-1/2} (dsv broadcast via LDS float4) ----
  vh[c] = dsv;
#pragma unroll
  for (int g = 0; g < 8; ++g) {
    float4 D4 = *(const float4*)(vh + 4 * g);
#pragma unroll
    for (int e = 0; e < 4; ++e) x[4 * g + e] *= f4c(D4, e) * dsv;
  }

  // ---- Householder tridiagonalization; d/e2 streamed to the LDS stash
  //      (wave-uniform values; keeping them in VGPRs alongside x[32] was
  //      architectural overpressure) ----
  float e2max = 0.0f, dminv = 1e30f, dmaxv = -1e30f;
#pragma unroll
  for (int k = 0; k < 30; ++k) {
    float colv = x[k];
    float dkk  = __shfl(x[k], k, 32);          // A[k][k], final at step k
    dminv = fminf(dminv, dkk); dmaxv = fmaxf(dmaxv, dkk);
    float sq    = (c > k) ? colv * colv : 0.0f;
    float sigma = red32(sq);                   // ||A[k+1:,k]||^2
    float akk1  = __shfl(x[k], k + 1, 32);
    e2max = fmaxf(e2max, sigma);
    sh[k] = dkk;                               // stash d[k]
    sh[32 + k] = sigma;                        // stash e2[k]
    float nrm   = fsqrt_(sigma);
    float alpha = (akk1 >= 0.0f) ? -nrm : nrm;
    float denom = fmaf(-alpha, akk1, sigma);   // vTv/2
    float tau   = frcp(fmaxf(denom, 1e-35f));  // sigma==0 -> v==0 no-op
    float v     = (c == k + 1) ? (akk1 - alpha) : ((c > k + 1) ? colv : 0.0f);
    vh[c] = v;                                 // broadcast v via LDS
    float acc = 0.0f;
#pragma unroll
    for (int g = 0; g < 8; ++g) {              // acc_c = sum_j A[j][c] v_j
      if (4 * g + 3 <= k) continue;
      float4 V4 = *(const float4*)(vh + 4 * g);
#pragma unroll
      for (int e = 0; e < 4; ++e) {
        int j = 4 * g + e;
        if (j > k) acc = fmaf(x[j], f4c(V4, e), acc);
      }
    }
    float p = tau * acc;
    float K = 0.5f * tau * red32(v * p);
    float q = fmaf(-K, v, p);
    qh[c] = q;                                 // broadcast q via LDS
#pragma unroll
    for (int g = 0; g < 8; ++g) {              // A -= v q^T + q v^T
      if (4 * g + 3 <= k) continue;
      float4 V4 = *(const float4*)(vh + 4 * g);
      float4 Q4 = *(const float4*)(qh + 4 * g);
#pragma unroll
      for (int e = 0; e < 4; ++e) {
        int j = 4 * g + e;
        if (j > k) x[j] = fmaf(-v, f4c(Q4, e), fmaf(-q, f4c(V4, e), x[j]));
      }
    }
    SCHED_FENCE();                             // biggest pressure site: pin hard
  }
  {
    float d30 = __shfl(x[30], 30, 32);
    float d31 = __shfl(x[31], 31, 32);
    float el  = __shfl(x[30], 31, 32);         // trailing subdiagonal
    float e30 = el * el;
    sh[30] = d30; sh[31] = d31; sh[62] = e30;
    e2max = fmaxf(e2max, e30);
    dminv = fminf(dminv, fminf(d30, d31));
    dmaxv = fmaxf(dmaxv, fmaxf(d30, d31));
  }
  // x[] dead from here -> its registers take d/e2 back; no live-range overlap

  // ---- reload wave-uniform d/e2 from the stash (float4 broadcast reads) ----
  float d[32], e2[31];
#pragma unroll
  for (int g = 0; g < 8; ++g) {
    float4 D4 = *(const float4*)(sh + 4 * g);
    d[4 * g + 0] = D4.x; d[4 * g + 1] = D4.y;
    d[4 * g + 2] = D4.z; d[4 * g + 3] = D4.w;
  }
#pragma unroll
  for (int g = 0; g < 8; ++g) {
    float4 E4 = *(const float4*)(sh + 32 + 4 * g);
    e2[4 * g + 0] = E4.x;
    if (4 * g + 1 < 31) e2[4 * g + 1] = E4.y;
    if (4 * g + 2 < 31) e2[4 * g + 2] = E4.z;
    if (4 * g + 3 < 31) e2[4 * g + 3] = E4.w;   // g=7: sh[63] unused, skipped
  }

  // ---- Gershgorin bounds ----
  float er = 2.0f * fsqrt_(e2max);
  float lo = fmaxf(dminv - er, 1e-3f);
  float hi = dmaxv + er;

  // ---- bisection with Sturm counts: lane c -> eigenvalue #c (pure VALU) ----
  // Lean form (round 5): no clamp (IEEE self-heals: qq->0 => rcp->inf =>
  // next qq -> -inf => rcp -> -0 => recovers; NaN needs exactly-zero e2,
  // measure-zero here), sign-bit-shift counting, 15 iters (err <= ~20/2^16
  // per eigenvalue => per-matrix d error <~0.009 worst-case vs 0.0756
  // threshold on the batch mean).
  for (int it = 0; it < 15; ++it) {
    float mid = 0.5f * (lo + hi);
    float qq  = d[0] - mid;
    int cnt = (int)(__float_as_uint(qq) >> 31);
#pragma unroll
    for (int i = 1; i < 32; ++i) {
      qq = (d[i] - mid) - e2[i - 1] * frcp(qq);
      cnt += (int)(__float_as_uint(qq) >> 31);
    }
    bool le = (cnt <= c);
    lo = le ? mid : lo;
    hi = le ? hi : mid;
  }

  float lam = 0.5f * (lo + hi);
  float lg  = __logf(lam);
  float s   = red32(lg * lg);
  float db  = fsqrt_(s);                       // d(x_b, y_b)

  if (c == 0) psum[hw] = db;
  __syncthreads();
  if (tid == 0) {
    float t = 0.0f;
#pragma unroll
    for (int i = 0; i < MPB; ++i) t += psum[i];
    partial[blockIdx.x] = t;
  }
}

__global__ __launch_bounds__(256) void riem_finish(const float* __restrict__ partial,
                                                   float* __restrict__ out) {
  float acc = 0.0f;
  for (int i = threadIdx.x; i < NBLK; i += 256) acc += partial[i];
  acc += __shfl_xor(acc, 1);
  acc += __shfl_xor(acc, 2);
  acc += __shfl_xor(acc, 4);
  acc += __shfl_xor(acc, 8);
  acc += __shfl_xor(acc, 16);
  acc += __shfl_xor(acc, 32);
  __shared__ float ps[4];
  if ((threadIdx.x & 63) == 0) ps[threadIdx.x >> 6] = acc;
  __syncthreads();
  if (threadIdx.x == 0)
    out[0] = (ps[0] + ps[1] + ps[2] + ps[3]) * (1.0f / (float)NMAT);
}

extern "C" void kernel_launch(void* const* d_in, const int* in_sizes, int n_in,
                              void* d_out, int out_size, void* d_ws, size_t ws_size,
                              hipStream_t stream) {
  const float* x = (const float*)d_in[0];
  const float* y = (const float*)d_in[1];
  float* out  = (float*)d_out;
  float* part = (float*)d_ws;   // NBLK floats = 25 KB
  riem_batch<<<NBLK, 256, 0, stream>>>(x, y, part);
  riem_finish<<<1, 256, 0, stream>>>(part, out);
}

// Round 6
// 703.687 us; speedup vs baseline: 2.5148x; 1.1437x over previous
//
#include <hip/hip_runtime.h>
#include <math.h>

#define NMAT 50000
#define MPB 8                    // matrices per block: 256 thr = 4 waves = 8 half-waves
#define NBLK (NMAT / MPB)        // 6250

// packed f32 pair -> v_pk_fma_f32 / v_pk_mul_f32 / v_pk_add_f32 (gfx90a+).
// MI355X's 157.3 TF f32 spec peak REQUIRES packed f32 (256CU*64ln*2flop*2pk*2.4G);
// scalar v_fma_f32 tops out at half that. This kernel is VALU-issue-bound
// (round-5: VALUBusy 92-96%), so packing the fma-dense loops halves their slots.
typedef __attribute__((ext_vector_type(2))) float f32x2;
#define EL(a, i) (a[(i) >> 1][(i) & 1])   // compile-time i only

__device__ __forceinline__ f32x2 pkfma(f32x2 a, f32x2 b, f32x2 c) {
  return __builtin_elementwise_fma(a, b, c);
}

__device__ __forceinline__ float frcp(float x)  { return __builtin_amdgcn_rcpf(x); }
__device__ __forceinline__ float frsq(float x)  { return __builtin_amdgcn_rsqf(x); }
__device__ __forceinline__ float fsqrt_(float x){ return __builtin_amdgcn_sqrtf(x); }

// Scheduler fence at unrolled-iteration boundaries: stops the machine
// scheduler from hoisting LDS reads across iterations. Round-4 evidence: this
// alone removed ~1.9 GB of scratch traffic (WRITE 1.91e6 -> 195 KB), VGPR
// 128 -> 76, dur 1385 -> 645 us. Do not remove.
#define SCHED_FENCE() __builtin_amdgcn_sched_barrier(0)

// x + rotate-right-by-n within rows of 16 (VALU pipe, not LDS pipe)
#define DPP_ROR_ADD(x, ctrl) \
  ((x) + __int_as_float(__builtin_amdgcn_update_dpp(0, __float_as_int(x), (ctrl), 0xF, 0xF, false)))

// sum across the 32-lane half-wave, all lanes get the result.
__device__ __forceinline__ float red32(float x) {
  x = DPP_ROR_ADD(x, 0x121);   // row_ror:1
  x = DPP_ROR_ADD(x, 0x122);   // row_ror:2
  x = DPP_ROR_ADD(x, 0x124);   // row_ror:4
  x = DPP_ROR_ADD(x, 0x128);   // row_ror:8
  x += __shfl_xor(x, 16, 32);
  return x;
}

__device__ __forceinline__ float f4c(const float4& v, int e) {
  return e == 0 ? v.x : e == 1 ? v.y : e == 2 ? v.z : v.w;   // e is compile-time
}

// (256,2): 128-VGPR cap -> up to 4 waves/SIMD; LDS 37.3KB -> 4 blocks/CU.
__global__ __launch_bounds__(256, 2) void riem_batch(const float* __restrict__ X,
                                                     const float* __restrict__ Y,
                                                     float* __restrict__ partial) {
  const int tid = threadIdx.x;
  const int c   = tid & 31;        // column owned by this lane
  const int hw  = tid >> 5;        // half-wave id within block (0..7)
  const long mat = (long)blockIdx.x * MPB + hw;
  const float* Yp = Y + mat * 1024;
  const float* Xp = X + mat * 1024;

  // Lb[h][j*32+i] = L[i][j] (column j contiguous -> conflict-free writes,
  // uniform-address float4 broadcast reads). No padding needed.
  __shared__ __align__(16) float Lb[MPB][1024];
  __shared__ __align__(16) float vb[MPB][32];
  __shared__ __align__(16) float qb[MPB][32];
  __shared__ __align__(16) float sb[MPB][64];   // d/e2 stash: [0..31]=d, [32..62]=e2
  __shared__ float psum[MPB];

  float* Lh = Lb[hw];
  float* vh = vb[hw];
  float* qh = qb[hw];
  float* sh = sb[hw];

  // ---- load Y columns: lane c holds Y[:,c] ----
  f32x2 m2[16];
#pragma unroll
  for (int i = 0; i < 32; ++i) EL(m2, i) = Yp[i * 32 + c];

  // ---- square-root-free symmetric elimination Y = L D L^T, L -> LDS ----
  // Packed pairs: a pair (i0,i1)=(2p,2p+1) is active iff i1>j. Boundary pair
  // (i0==j, j even) is packed anyway: it updates m[j] via L[j][j]~1, and m[j]
  // is dead after this step (piv/mj/Lh-write already extracted). Active pairs
  // never touch the junk region i<j of Lh.
  float dc = 1.0f;
#pragma unroll
  for (int j = 0; j < 32; ++j) {
    float mjv  = EL(m2, j);                    // M[j][c] per lane
    float piv  = __shfl(mjv, j, 32);           // D[j], uniform per half-wave
    float rinv = frcp(piv);
    if (c == j) dc = piv;
    Lh[j * 32 + c] = mjv * rinv;               // L[c][j]; diag~1; junk for c<j (never read)
    f32x2 mj2 = { mjv, mjv };
#pragma unroll
    for (int g = 0; g < 8; ++g) {
      if (4 * g + 3 <= j) continue;            // group has no active pair
      float4 L4 = *(const float4*)(Lh + j * 32 + 4 * g);   // uniform broadcast read
      if (4 * g + 1 > j) {                     // pair A (4g,4g+1)
        f32x2 l = { L4.x, L4.y };
        m2[2 * g] = pkfma(-l, mj2, m2[2 * g]);
      }
      if (4 * g + 3 > j) {                     // pair B (4g+2,4g+3)
        f32x2 l = { L4.z, L4.w };
        m2[2 * g + 1] = pkfma(-l, mj2, m2[2 * g + 1]);
      }
    }
    SCHED_FENCE();                             // no cross-iteration hoisting
  }
  float dsv = frsq(dc);                        // D[c]^{-1/2}
  // m2[] dead from here

  // ---- load X, forward solve W = L^{-1} X ----
  // x[k] is the LIVE solution element -> boundary pair (i0==k) must not touch
  // it: scalar fma on i1 only. Fully-active pairs packed.
  f32x2 x2[16];
#pragma unroll
  for (int i = 0; i < 32; ++i) EL(x2, i) = Xp[i * 32 + c];
#pragma unroll
  for (int k = 0; k < 31; ++k) {
    float xk = EL(x2, k);
    f32x2 xk2 = { xk, xk };
#pragma unroll
    for (int g = 0; g < 8; ++g) {
      if (4 * g + 3 <= k) continue;
      float4 L4 = *(const float4*)(Lh + k * 32 + 4 * g);
      if (4 * g > k) {                         // pair A fully active
        f32x2 l = { L4.x, L4.y };
        x2[2 * g] = pkfma(-l, xk2, x2[2 * g]);
      } else if (4 * g == k) {                 // boundary: scalar on i1
        EL(x2, 4 * g + 1) = fmaf(-L4.y, xk, EL(x2, 4 * g + 1));
      }
      if (4 * g + 2 > k) {                     // pair B fully active
        f32x2 l = { L4.z, L4.w };
        x2[2 * g + 1] = pkfma(-l, xk2, x2[2 * g + 1]);
      } else if (4 * g + 2 == k) {             // boundary: scalar on i1
        EL(x2, 4 * g + 3) = fmaf(-L4.w, xk, EL(x2, 4 * g + 3));
      }
    }
    SCHED_FENCE();
  }

  // ---- in-register 32x32 butterfly transpose (block-swap recursion) ----
#pragma unroll
  for (int s = 16; s >= 1; s >>= 1) {
    const bool up = (c & s) != 0;
#pragma unroll
    for (int i = 0; i < 32; ++i) {
      if (i & s) continue;                     // compile-time skip
      const int h2 = i | s;
      float send = up ? EL(x2, i) : EL(x2, h2);
      float rec  = __shfl_xor(send, s, 32);
      EL(x2, i)  = up ? rec : EL(x2, i);
      EL(x2, h2) = up ? EL(x2, h2) : rec;
    }
  }

  // ---- second solve V = L^{-1} W^T ----
#pragma unroll
  for (int k = 0; k < 31; ++k) {
    float xk = EL(x2, k);
    f32x2 xk2 = { xk, xk };
#pragma unroll
    for (int g = 0; g < 8; ++g) {
      if (4 * g + 3 <= k) continue;
      float4 L4 = *(const float4*)(Lh + k * 32 + 4 * g);
      if (4 * g > k) {
        f32x2 l = { L4.x, L4.y };
        x2[2 * g] = pkfma(-l, xk2, x2[2 * g]);
      } else if (4 * g == k) {
        EL(x2, 4 * g + 1) = fmaf(-L4.y, xk, EL(x2, 4 * g + 1));
      }
      if (4 * g + 2 > k) {
        f32x2 l = { L4.z, L4.w };
        x2[2 * g + 1] = pkfma(-l, xk2, x2[2 * g + 1]);
      } else if (4 * g + 2 == k) {
        EL(x2, 4 * g + 3) = fmaf(-L4.w, xk, EL(x2, 4 * g + 3));
      }
    }
    SCHED_FENCE();
  }

  // ---- A = D^{-1/2} V D^{-1/2} (dsv broadcast via LDS float4, packed mul) ----
  vh[c] = dsv;
  {
    f32x2 dsv2 = { dsv, dsv };
#pragma unroll
    for (int g = 0; g < 8; ++g) {
      float4 D4 = *(const float4*)(vh + 4 * g);
      f32x2 a = { D4.x, D4.y };
      f32x2 b = { D4.z, D4.w };
      x2[2 * g]     = x2[2 * g]     * a * dsv2;
      x2[2 * g + 1] = x2[2 * g + 1] * b * dsv2;
    }
  }

  // ---- Householder tridiagonalization; d/e2 streamed to the LDS stash.
  // Packed pairs, active iff i1>k. Boundary pair (i0==k, k even) is packed:
  // matvec is protected by v[c<=k]=0 (vh holds those zeros); rank-2 corrupts
  // x[k] only, which is dead after this step's header reads (colv/dkk/akk1
  // all read before the update; later steps only touch j>k'>=k+1). ----
  float e2max = 0.0f, dminv = 1e30f, dmaxv = -1e30f;
#pragma unroll
  for (int k = 0; k < 30; ++k) {
    float colv = EL(x2, k);
    float dkk  = __shfl(colv, k, 32);          // A[k][k], final at step k
    dminv = fminf(dminv, dkk); dmaxv = fmaxf(dmaxv, dkk);
    float sq    = (c > k) ? colv * colv : 0.0f;
    float sigma = red32(sq);                   // ||A[k+1:,k]||^2
    float akk1  = __shfl(colv, k + 1, 32);
    e2max = fmaxf(e2max, sigma);
    sh[k] = dkk;                               // stash d[k]
    sh[32 + k] = sigma;                        // stash e2[k]
    float nrm   = fsqrt_(sigma);
    float alpha = (akk1 >= 0.0f) ? -nrm : nrm;
    float denom = fmaf(-alpha, akk1, sigma);   // vTv/2
    float tau   = frcp(fmaxf(denom, 1e-35f));  // sigma==0 -> v==0 no-op
    float v     = (c == k + 1) ? (akk1 - alpha) : ((c > k + 1) ? colv : 0.0f);
    vh[c] = v;                                 // broadcast v via LDS (0 for c<=k)
    f32x2 acc2 = { 0.0f, 0.0f };
#pragma unroll
    for (int g = 0; g < 8; ++g) {              // acc_c = sum_j A[j][c] v_j
      if (4 * g + 3 <= k) continue;
      float4 V4 = *(const float4*)(vh + 4 * g);
      if (4 * g + 1 > k) {
        f32x2 vv = { V4.x, V4.y };
        acc2 = pkfma(x2[2 * g], vv, acc2);
      }
      if (4 * g + 3 > k) {
        f32x2 vv = { V4.z, V4.w };
        acc2 = pkfma(x2[2 * g + 1], vv, acc2);
      }
    }
    float acc = acc2.x + acc2.y;
    float p = tau * acc;
    float K = 0.5f * tau * red32(v * p);
    float q = fmaf(-K, v, p);
    qh[c] = q;                                 // broadcast q via LDS
    f32x2 vl = { v, v };
    f32x2 ql = { q, q };
#pragma unroll
    for (int g = 0; g < 8; ++g) {              // A -= v q^T + q v^T
      if (4 * g + 3 <= k) continue;
      float4 V4 = *(const float4*)(vh + 4 * g);
      float4 Q4 = *(const float4*)(qh + 4 * g);
      if (4 * g + 1 > k) {
        f32x2 qv = { Q4.x, Q4.y };
        f32x2 vv = { V4.x, V4.y };
        f32x2 t = pkfma(-vl, qv, x2[2 * g]);
        x2[2 * g] = pkfma(-ql, vv, t);
      }
      if (4 * g + 3 > k) {
        f32x2 qv = { Q4.z, Q4.w };
        f32x2 vv = { V4.z, V4.w };
        f32x2 t = pkfma(-vl, qv, x2[2 * g + 1]);
        x2[2 * g + 1] = pkfma(-ql, vv, t);
      }
    }
    SCHED_FENCE();                             // biggest pressure site: pin hard
  }
  {
    float d30 = __shfl(EL(x2, 30), 30, 32);
    float d31 = __shfl(EL(x2, 31), 31, 32);
    float el  = __shfl(EL(x2, 30), 31, 32);    // trailing subdiagonal
    float e30 = el * el;
    sh[30] = d30; sh[31] = d31; sh[62] = e30;
    e2max = fmaxf(e2max, e30);
    dminv = fminf(dminv, fminf(d30, d31));
    dmaxv = fmaxf(dmaxv, fmaxf(d30, d31));
  }
  // x2[] dead from here -> its registers take d/e2 back; no live-range overlap

  // ---- reload wave-uniform d/e2 from the stash (float4 broadcast reads) ----
  f32x2 d2[16];
  float e2[31];
#pragma unroll
  for (int g = 0; g < 8; ++g) {
    float4 D4 = *(const float4*)(sh + 4 * g);
    f32x2 a = { D4.x, D4.y };
    f32x2 b = { D4.z, D4.w };
    d2[2 * g] = a; d2[2 * g + 1] = b;
  }
#pragma unroll
  for (int g = 0; g < 8; ++g) {
    float4 E4 = *(const float4*)(sh + 32 + 4 * g);
    e2[4 * g + 0] = E4.x;
    if (4 * g + 1 < 31) e2[4 * g + 1] = E4.y;
    if (4 * g + 2 < 31) e2[4 * g + 2] = E4.z;
    if (4 * g + 3 < 31) e2[4 * g + 3] = E4.w;   // g=7: sh[63] unused, skipped
  }

  // ---- Gershgorin bounds ----
  float er = 2.0f * fsqrt_(e2max);
  float lo = fmaxf(dminv - er, 1e-3f);
  float hi = dmaxv + er;

  // ---- bisection with Sturm counts: lane c -> eigenvalue #c (pure VALU) ----
  // No clamp (IEEE self-heals; see r5), sign-bit counting, packed d-mid
  // precompute (16 pk_sub vs 32 v_sub per iter). 12 iters: midpoint error is
  // unbiased and averages out over 1.6M eigenvalues; mean-threshold margin is
  // >50x (absmax was 0.0 at 15 iters).
  for (int it = 0; it < 12; ++it) {
    float mid = 0.5f * (lo + hi);
    f32x2 mid2 = { mid, mid };
    f32x2 dm2[16];
#pragma unroll
    for (int pp = 0; pp < 16; ++pp) dm2[pp] = d2[pp] - mid2;
    float qq = EL(dm2, 0);
    int cnt = (int)(__float_as_uint(qq) >> 31);
#pragma unroll
    for (int i = 1; i < 32; ++i) {
      qq = fmaf(-e2[i - 1], frcp(qq), EL(dm2, i));
      cnt += (int)(__float_as_uint(qq) >> 31);
    }
    bool le = (cnt <= c);
    lo = le ? mid : lo;
    hi = le ? hi : mid;
  }

  float lam = 0.5f * (lo + hi);
  float lg  = __logf(lam);
  float s   = red32(lg * lg);
  float db  = fsqrt_(s);                       // d(x_b, y_b)

  if (c == 0) psum[hw] = db;
  __syncthreads();
  if (tid == 0) {
    float t = 0.0f;
#pragma unroll
    for (int i = 0; i < MPB; ++i) t += psum[i];
    partial[blockIdx.x] = t;
  }
}

__global__ __launch_bounds__(256) void riem_finish(const float* __restrict__ partial,
                                                   float* __restrict__ out) {
  float acc = 0.0f;
  for (int i = threadIdx.x; i < NBLK; i += 256) acc += partial[i];
  acc += __shfl_xor(acc, 1);
  acc += __shfl_xor(acc, 2);
  acc += __shfl_xor(acc, 4);
  acc += __shfl_xor(acc, 8);
  acc += __shfl_xor(acc, 16);
  acc += __shfl_xor(acc, 32);
  __shared__ float ps[4];
  if ((threadIdx.x & 63) == 0) ps[threadIdx.x >> 6] = acc;
  __syncthreads();
  if (threadIdx.x == 0)
    out[0] = (ps[0] + ps[1] + ps[2] + ps[3]) * (1.0f / (float)NMAT);
}

extern "C" void kernel_launch(void* const* d_in, const int* in_sizes, int n_in,
                              void* d_out, int out_size, void* d_ws, size_t ws_size,
                              hipStream_t stream) {
  const float* x = (const float*)d_in[0];
  const float* y = (const float*)d_in[1];
  float* out  = (float*)d_out;
  float* part = (float*)d_ws;   // NBLK floats = 25 KB
  riem_batch<<<NBLK, 256, 0, stream>>>(x, y, part);
  riem_finish<<<1, 256, 0, stream>>>(part, out);
}

// Round 7
// 691.224 us; speedup vs baseline: 2.5602x; 1.0180x over previous
//
#include <hip/hip_runtime.h>
#include <math.h>

#define NMAT 50000
#define MPB 8                    // matrices per block: 256 thr = 4 waves = 8 half-waves
#define NBLK (NMAT / MPB)        // 6250

// packed f32 pair -> v_pk_fma_f32 / v_pk_mul_f32 / v_pk_add_f32 (gfx90a+).
// MI355X's 157.3 TF f32 spec peak REQUIRES packed f32; scalar v_fma_f32 is
// half rate. Kernel is VALU-issue-bound (r5/r6: VALUBusy 92-96%).
typedef __attribute__((ext_vector_type(2))) float f32x2;
#define EL(a, i) (a[(i) >> 1][(i) & 1])   // compile-time i only

__device__ __forceinline__ f32x2 pkfma(f32x2 a, f32x2 b, f32x2 c) {
  return __builtin_elementwise_fma(a, b, c);
}

__device__ __forceinline__ float frcp(float x)  { return __builtin_amdgcn_rcpf(x); }
__device__ __forceinline__ float frsq(float x)  { return __builtin_amdgcn_rsqf(x); }
__device__ __forceinline__ float fsqrt_(float x){ return __builtin_amdgcn_sqrtf(x); }

// Scheduler fence at unrolled-iteration boundaries: stops the machine
// scheduler from hoisting LDS reads across iterations. Round-4 evidence: this
// alone removed ~1.9 GB of scratch traffic (WRITE 1.91e6 -> 195 KB), VGPR
// 128 -> 76, dur 1385 -> 645 us. Do not remove.
#define SCHED_FENCE() __builtin_amdgcn_sched_barrier(0)

// x + rotate-right-by-n within rows of 16 (VALU pipe, not LDS pipe)
#define DPP_ROR_ADD(x, ctrl) \
  ((x) + __int_as_float(__builtin_amdgcn_update_dpp(0, __float_as_int(x), (ctrl), 0xF, 0xF, false)))

// sum across the 32-lane half-wave, all lanes get the result.
__device__ __forceinline__ float red32(float x) {
  x = DPP_ROR_ADD(x, 0x121);   // row_ror:1
  x = DPP_ROR_ADD(x, 0x122);   // row_ror:2
  x = DPP_ROR_ADD(x, 0x124);   // row_ror:4
  x = DPP_ROR_ADD(x, 0x128);   // row_ror:8
  x += __shfl_xor(x, 16, 32);
  return x;
}

// (256,2): 128-VGPR cap -> up to 4 waves/SIMD; LDS 37.3KB -> 4 blocks/CU.
__global__ __launch_bounds__(256, 2) void riem_batch(const float* __restrict__ X,
                                                     const float* __restrict__ Y,
                                                     float* __restrict__ partial) {
  const int tid = threadIdx.x;
  const int c   = tid & 31;        // column owned by this lane
  const int hw  = tid >> 5;        // half-wave id within block (0..7)
  const long mat = (long)blockIdx.x * MPB + hw;
  const float* Yp = Y + mat * 1024;
  const float* Xp = X + mat * 1024;

  // Lb[h][j*32+i] = L[i][j] (column j contiguous -> conflict-free writes,
  // uniform-address float4 broadcast reads). No padding needed.
  __shared__ __align__(16) float Lb[MPB][1024];
  __shared__ __align__(16) float vb[MPB][32];
  __shared__ __align__(16) float qb[MPB][32];
  __shared__ __align__(16) float sb[MPB][64];   // d/e2 stash: [0..31]=d, [32..62]=e2
  __shared__ float psum[MPB];

  float* Lh = Lb[hw];
  float* vh = vb[hw];
  float* qh = qb[hw];
  float* sh = sb[hw];

  // ---- load Y and X columns: lane c holds Y[:,c] and X[:,c].
  // X loaded early: its solve is FUSED into the elimination below, and the
  // global-load latency hides under the Cholesky headers. ----
  f32x2 m2[16];
  f32x2 x2[16];
#pragma unroll
  for (int i = 0; i < 32; ++i) EL(m2, i) = Yp[i * 32 + c];
#pragma unroll
  for (int i = 0; i < 32; ++i) EL(x2, i) = Xp[i * 32 + c];

  // ---- fused: Y = L D L^T elimination AND forward solve W = L^{-1} X.
  // At step j, x[j] is final (only steps j'<j update it), so solve1's step j
  // can run here, sharing the L4 registers the m-update just loaded. Deletes
  // solve1's entire second pass over Lh (8 ds_read_b128 + header x31 steps).
  // Packed-pair rules: pair (i0,i1)=(2p,2p+1) active iff i1>j.
  //   m-path: boundary pair (i0==j) packed anyway -- m[j] is dead after the
  //           header (piv/mjv/Lh-write extracted).
  //   x-path: x[j] is LIVE (it is the solution element) -> boundary pair does
  //           a scalar fma on i1 only.
  float dc = 1.0f;
#pragma unroll
  for (int j = 0; j < 32; ++j) {
    float mjv  = EL(m2, j);                    // M[j][c] per lane
    float piv  = __shfl(mjv, j, 32);           // D[j], uniform per half-wave
    float rinv = frcp(piv);
    if (c == j) dc = piv;
    Lh[j * 32 + c] = mjv * rinv;               // L[c][j]; diag~1; junk for c<j (never read)
    float xj = EL(x2, j);                      // final solution element j
    f32x2 mj2 = { mjv, mjv };
    f32x2 xj2 = { xj, xj };
#pragma unroll
    for (int g = 0; g < 8; ++g) {
      if (4 * g + 3 <= j) continue;            // group has no active pair
      float4 L4 = *(const float4*)(Lh + j * 32 + 4 * g);   // uniform broadcast read
      if (4 * g > j) {                         // pair A (4g,4g+1) fully active
        f32x2 l = { L4.x, L4.y };
        m2[2 * g] = pkfma(-l, mj2, m2[2 * g]);
        x2[2 * g] = pkfma(-l, xj2, x2[2 * g]);
      } else if (4 * g + 1 > j) {              // boundary: j == 4g (j even)
        f32x2 l = { L4.x, L4.y };
        m2[2 * g] = pkfma(-l, mj2, m2[2 * g]);            // m[j] dead: packed OK
        EL(x2, 4 * g + 1) = fmaf(-L4.y, xj, EL(x2, 4 * g + 1));  // protect x[j]
      }
      if (4 * g + 2 > j) {                     // pair B (4g+2,4g+3) fully active
        f32x2 l = { L4.z, L4.w };
        m2[2 * g + 1] = pkfma(-l, mj2, m2[2 * g + 1]);
        x2[2 * g + 1] = pkfma(-l, xj2, x2[2 * g + 1]);
      } else if (4 * g + 3 > j) {              // boundary: j == 4g+2
        f32x2 l = { L4.z, L4.w };
        m2[2 * g + 1] = pkfma(-l, mj2, m2[2 * g + 1]);
        EL(x2, 4 * g + 3) = fmaf(-L4.w, xj, EL(x2, 4 * g + 3));
      }
    }
    SCHED_FENCE();                             // no cross-iteration hoisting
  }
  float dsv = frsq(dc);                        // D[c]^{-1/2}
  // m2[] dead from here; x2[] = W = L^{-1} X

  // ---- in-register 32x32 butterfly transpose (block-swap recursion) ----
#pragma unroll
  for (int s = 16; s >= 1; s >>= 1) {
    const bool up = (c & s) != 0;
#pragma unroll
    for (int i = 0; i < 32; ++i) {
      if (i & s) continue;                     // compile-time skip
      const int h2 = i | s;
      float send = up ? EL(x2, i) : EL(x2, h2);
      float rec  = __shfl_xor(send, s, 32);
      EL(x2, i)  = up ? rec : EL(x2, i);
      EL(x2, h2) = up ? EL(x2, h2) : rec;
    }
  }

  // ---- second solve V = L^{-1} W^T ----
#pragma unroll
  for (int k = 0; k < 31; ++k) {
    float xk = EL(x2, k);
    f32x2 xk2 = { xk, xk };
#pragma unroll
    for (int g = 0; g < 8; ++g) {
      if (4 * g + 3 <= k) continue;
      float4 L4 = *(const float4*)(Lh + k * 32 + 4 * g);
      if (4 * g > k) {
        f32x2 l = { L4.x, L4.y };
        x2[2 * g] = pkfma(-l, xk2, x2[2 * g]);
      } else if (4 * g == k) {
        EL(x2, 4 * g + 1) = fmaf(-L4.y, xk, EL(x2, 4 * g + 1));
      }
      if (4 * g + 2 > k) {
        f32x2 l = { L4.z, L4.w };
        x2[2 * g + 1] = pkfma(-l, xk2, x2[2 * g + 1]);
      } else if (4 * g + 2 == k) {
        EL(x2, 4 * g + 3) = fmaf(-L4.w, xk, EL(x2, 4 * g + 3));
      }
    }
    SCHED_FENCE();
  }

  // ---- A = D^{-1/2} V D^{-1/2} (dsv broadcast via LDS float4, packed mul) ----
  vh[c] = dsv;
  {
    f32x2 dsv2 = { dsv, dsv };
#pragma unroll
    for (int g = 0; g < 8; ++g) {
      float4 D4 = *(const float4*)(vh + 4 * g);
      f32x2 a = { D4.x, D4.y };
      f32x2 b = { D4.z, D4.w };
      x2[2 * g]     = x2[2 * g]     * a * dsv2;
      x2[2 * g + 1] = x2[2 * g + 1] * b * dsv2;
    }
  }

  // ---- Householder tridiagonalization; d/e2 streamed to the LDS stash.
  // Packed pairs, active iff i1>k. Boundary pair (i0==k, k even) is packed:
  // matvec is protected by v[c<=k]=0 (vh holds those zeros); rank-2 corrupts
  // x[k] only, which is dead after this step's header reads. ----
  float e2max = 0.0f, dminv = 1e30f, dmaxv = -1e30f;
#pragma unroll
  for (int k = 0; k < 30; ++k) {
    float colv = EL(x2, k);
    float dkk  = __shfl(colv, k, 32);          // A[k][k], final at step k
    dminv = fminf(dminv, dkk); dmaxv = fmaxf(dmaxv, dkk);
    float sq    = (c > k) ? colv * colv : 0.0f;
    float sigma = red32(sq);                   // ||A[k+1:,k]||^2
    float akk1  = __shfl(colv, k + 1, 32);
    e2max = fmaxf(e2max, sigma);
    sh[k] = dkk;                               // stash d[k]
    sh[32 + k] = sigma;                        // stash e2[k]
    float nrm   = fsqrt_(sigma);
    float alpha = (akk1 >= 0.0f) ? -nrm : nrm;
    float denom = fmaf(-alpha, akk1, sigma);   // vTv/2
    float tau   = frcp(fmaxf(denom, 1e-35f));  // sigma==0 -> v==0 no-op
    float v     = (c == k + 1) ? (akk1 - alpha) : ((c > k + 1) ? colv : 0.0f);
    vh[c] = v;                                 // broadcast v via LDS (0 for c<=k)
    f32x2 acc2 = { 0.0f, 0.0f };
#pragma unroll
    for (int g = 0; g < 8; ++g) {              // acc_c = sum_j A[j][c] v_j
      if (4 * g + 3 <= k) continue;
      float4 V4 = *(const float4*)(vh + 4 * g);
      if (4 * g + 1 > k) {
        f32x2 vv = { V4.x, V4.y };
        acc2 = pkfma(x2[2 * g], vv, acc2);
      }
      if (4 * g + 3 > k) {
        f32x2 vv = { V4.z, V4.w };
        acc2 = pkfma(x2[2 * g + 1], vv, acc2);
      }
    }
    float acc = acc2.x + acc2.y;
    float p = tau * acc;
    float K = 0.5f * tau * red32(v * p);
    float q = fmaf(-K, v, p);
    qh[c] = q;                                 // broadcast q via LDS
    f32x2 vl = { v, v };
    f32x2 ql = { q, q };
#pragma unroll
    for (int g = 0; g < 8; ++g) {              // A -= v q^T + q v^T
      if (4 * g + 3 <= k) continue;
      float4 V4 = *(const float4*)(vh + 4 * g);
      float4 Q4 = *(const float4*)(qh + 4 * g);
      if (4 * g + 1 > k) {
        f32x2 qv = { Q4.x, Q4.y };
        f32x2 vv = { V4.x, V4.y };
        f32x2 t = pkfma(-vl, qv, x2[2 * g]);
        x2[2 * g] = pkfma(-ql, vv, t);
      }
      if (4 * g + 3 > k) {
        f32x2 qv = { Q4.z, Q4.w };
        f32x2 vv = { V4.z, V4.w };
        f32x2 t = pkfma(-vl, qv, x2[2 * g + 1]);
        x2[2 * g + 1] = pkfma(-ql, vv, t);
      }
    }
    SCHED_FENCE();                             // biggest pressure site: pin hard
  }
  {
    float d30 = __shfl(EL(x2, 30), 30, 32);
    float d31 = __shfl(EL(x2, 31), 31, 32);
    float el  = __shfl(EL(x2, 30), 31, 32);    // trailing subdiagonal
    float e30 = el * el;
    sh[30] = d30; sh[31] = d31; sh[62] = e30;
    e2max = fmaxf(e2max, e30);
    dminv = fminf(dminv, fminf(d30, d31));
    dmaxv = fmaxf(dmaxv, fmaxf(d30, d31));
  }
  // x2[] dead from here -> its registers take d/e2 back; no live-range overlap

  // ---- reload wave-uniform d/e2 from the stash (float4 broadcast reads) ----
  f32x2 d2[16];
  float e2[31];
#pragma unroll
  for (int g = 0; g < 8; ++g) {
    float4 D4 = *(const float4*)(sh + 4 * g);
    f32x2 a = { D4.x, D4.y };
    f32x2 b = { D4.z, D4.w };
    d2[2 * g] = a; d2[2 * g + 1] = b;
  }
#pragma unroll
  for (int g = 0; g < 8; ++g) {
    float4 E4 = *(const float4*)(sh + 32 + 4 * g);
    e2[4 * g + 0] = E4.x;
    if (4 * g + 1 < 31) e2[4 * g + 1] = E4.y;
    if (4 * g + 2 < 31) e2[4 * g + 2] = E4.z;
    if (4 * g + 3 < 31) e2[4 * g + 3] = E4.w;   // g=7: sh[63] unused, skipped
  }

  // ---- Gershgorin bounds ----
  float er = 2.0f * fsqrt_(e2max);
  float lo = fmaxf(dminv - er, 1e-3f);
  float hi = dmaxv + er;

  // ---- bisection with Sturm counts: lane c -> eigenvalue #c (pure VALU) ----
  // No clamp (IEEE self-heals), sign-bit counting, packed d-mid precompute,
  // 12 iters (midpoint error unbiased; averages over 1.6M eigenvalues;
  // absmax was 0.0 at 12 iters in round 6).
  for (int it = 0; it < 12; ++it) {
    float mid = 0.5f * (lo + hi);
    f32x2 mid2 = { mid, mid };
    f32x2 dm2[16];
#pragma unroll
    for (int pp = 0; pp < 16; ++pp) dm2[pp] = d2[pp] - mid2;
    float qq = EL(dm2, 0);
    int cnt = (int)(__float_as_uint(qq) >> 31);
#pragma unroll
    for (int i = 1; i < 32; ++i) {
      qq = fmaf(-e2[i - 1], frcp(qq), EL(dm2, i));
      cnt += (int)(__float_as_uint(qq) >> 31);
    }
    bool le = (cnt <= c);
    lo = le ? mid : lo;
    hi = le ? hi : mid;
  }

  float lam = 0.5f * (lo + hi);
  float lg  = __logf(lam);
  float s   = red32(lg * lg);
  float db  = fsqrt_(s);                       // d(x_b, y_b)

  if (c == 0) psum[hw] = db;
  __syncthreads();
  if (tid == 0) {
    float t = 0.0f;
#pragma unroll
    for (int i = 0; i < MPB; ++i) t += psum[i];
    partial[blockIdx.x] = t;
  }
}

__global__ __launch_bounds__(256) void riem_finish(const float* __restrict__ partial,
                                                   float* __restrict__ out) {
  float acc = 0.0f;
  for (int i = threadIdx.x; i < NBLK; i += 256) acc += partial[i];
  acc += __shfl_xor(acc, 1);
  acc += __shfl_xor(acc, 2);
  acc += __shfl_xor(acc, 4);
  acc += __shfl_xor(acc, 8);
  acc += __shfl_xor(acc, 16);
  acc += __shfl_xor(acc, 32);
  __shared__ float ps[4];
  if ((threadIdx.x & 63) == 0) ps[threadIdx.x >> 6] = acc;
  __syncthreads();
  if (threadIdx.x == 0)
    out[0] = (ps[0] + ps[1] + ps[2] + ps[3]) * (1.0f / (float)NMAT);
}

extern "C" void kernel_launch(void* const* d_in, const int* in_sizes, int n_in,
                              void* d_out, int out_size, void* d_ws, size_t ws_size,
                              hipStream_t stream) {
  const float* x = (const float*)d_in[0];
  const float* y = (const float*)d_in[1];
  float* out  = (float*)d_out;
  float* part = (float*)d_ws;   // NBLK floats = 25 KB
  riem_batch<<<NBLK, 256, 0, stream>>>(x, y, part);
  riem_finish<<<1, 256, 0, stream>>>(part, out);
}